// Round 11
// baseline (82.314 us; speedup 1.0000x reference)
//
#include <hip/hip_runtime.h>
#include <hip/hip_bf16.h>
#include <hip/hip_fp8.h>
#include <stdint.h>

// VQ: z (32,256,32,32) f32 NCHW, codebook (1024,256) f32
// out: z_q (8388608 f32 NCHW) + commit_loss (1 f32 at out[8388608])
//
// R11: collapse 4 kernels -> 2 (R10 at 45us had ~10us of fixed overhead:
// k0 ~3 + k3 ~2 + 3 graph gaps; both merged away).
// k1: per-block in-LDS codebook-quarter prep (f32->fp8 e4m3 x-512 frags +
// norms, same mapping as the verified k0) + R10 main loop (LDS-resident
// quarter, fp8 MFMA, encoded argmin (S&~0x3FF)|code) -> penc. Also resets
// the ws counter (block 0) for k2's last-block finisher.
// k2: 4-way merge + z_q gather/transpose/NCHW write + per-block loss
// partials; LAST block (threadfence+atomicAdd==511) does the deterministic
// fixed-order loss tree (former k3).

#define WS_PENC  0                 // 4*32768 f32 = 512 KB
#define WS_PART2 524288            // 128 f32 (z^2 partials)
#define WS_PART  524800            // 512 f32 (minS partials)
#define WS_CTR   526848            // 1 u32

typedef float f32x4 __attribute__((ext_vector_type(4)));
typedef long  i64;
typedef long  l64x2 __attribute__((ext_vector_type(2)));

template <bool HI>
static __device__ __forceinline__ unsigned pk2(float a, float b, unsigned old) {
#if __has_builtin(__builtin_amdgcn_cvt_pk_fp8_f32)
    return (unsigned)__builtin_amdgcn_cvt_pk_fp8_f32(a, b, (int)old, HI);
#else
    __hip_fp8_e4m3 qa(a), qb(b);
    unsigned w = (unsigned)qa.__x | ((unsigned)qb.__x << 8);
    return HI ? ((old & 0x0000FFFFu) | (w << 16)) : ((old & 0xFFFF0000u) | w);
#endif
}

// ---------------- K1: prep(LDS) + per-quarter distances + encoded argmin ----------------
__global__ __launch_bounds__(512) void k1_main(const float* __restrict__ z,
                                               const float* __restrict__ cb,
                                               float* __restrict__ penc,
                                               float* __restrict__ part2,
                                               unsigned* __restrict__ ctr) {
    __shared__ __align__(16) unsigned char lds[65536];
    __shared__ float cn_lds[256];
    __shared__ float redz[8];
    const int t = threadIdx.x, w = t >> 6, l = t & 63;
    const int col = l & 15, g4 = l >> 4, gc4 = g4 * 4;
    const int b = blockIdx.x, q = b >> 7, grp = b & 127;   // q-major: co-XCD per grp
    const int img = grp >> 2, hw0 = (grp & 3) << 8;        // 256 pos per group

    if (b == 0 && t == 0) *ctr = 0u;                       // reset finisher counter

    // ---- prep: quarter codebook f32 -> (-512*cb) fp8 frags in LDS + 256*norms ----
    // wave w handles code round*8+w; lane l holds k=4l..4l+3 (k0's verified map):
    // byteoff = ((chunk*4+kp)*64 + g4w*16 + r16)*16 + ksb*8 + lb*4
    {
        const int kp = l >> 4, ksb = (l >> 3) & 1, g4w = (l >> 1) & 3, lb = l & 1;
        const float4* cbq = (const float4*)cb + q * 256 * 64;
        for (int round = 0; round < 32; ++round) {
            const int code_local = round * 8 + w;
            const float4 v = cbq[code_local * 64 + l];
            float nrm = v.x * v.x + v.y * v.y + v.z * v.z + v.w * v.w;
            #pragma unroll
            for (int off = 1; off < 64; off <<= 1) nrm += __shfl_xor(nrm, off);
            if (l == 0) cn_lds[code_local] = 256.f * nrm;
            unsigned u = pk2<false>(-512.f * v.x, -512.f * v.y, 0u);
            u = pk2<true>(-512.f * v.z, -512.f * v.w, u);
            const int chunk = code_local >> 4, r16 = code_local & 15;
            const int byteoff = ((chunk * 4 + kp) * 64 + g4w * 16 + r16) * 16
                              + ksb * 8 + lb * 4;
            *(unsigned*)(lds + byteoff) = u;
        }
    }

    // ---- z -> fp8 B-frags (32 pos per wave) + z^2 (f32) ----
    const float* zp = z + img * 262144 + hw0 + w * 32;
    float z2 = 0.f;
    i64 zf[2][8];
    #pragma unroll
    for (int pf = 0; pf < 2; ++pf) {
        const int p = pf * 16 + col;
        #pragma unroll
        for (int ks = 0; ks < 8; ++ks) {
            const float* s0 = zp + (ks * 32 + g4 * 8) * 1024 + p;
            float v0 = s0[0], v1 = s0[1024], v2 = s0[2048], v3 = s0[3072];
            float v4 = s0[4096], v5 = s0[5120], v6 = s0[6144], v7 = s0[7168];
            z2 += v0*v0 + v1*v1 + v2*v2 + v3*v3 + v4*v4 + v5*v5 + v6*v6 + v7*v7;
            unsigned lo = pk2<false>(v0, v1, 0u); lo = pk2<true>(v2, v3, lo);
            unsigned hi = pk2<false>(v4, v5, 0u); hi = pk2<true>(v6, v7, hi);
            zf[pf][ks] = (i64)(((unsigned long)hi << 32) | (unsigned long)lo);
        }
    }
    __syncthreads();   // prep ds_writes visible

    float menc0 = __builtin_bit_cast(float, 0x7F7FFC00u);
    float menc1 = __builtin_bit_cast(float, 0x7F7FFC00u);

    i64 A0[8], A1[8];
#define LDA(DST, c) do {                                                         \
    _Pragma("unroll") for (int kp2 = 0; kp2 < 4; ++kp2) {                        \
        l64x2 u = *(const l64x2*)(lds + (((c) * 4 + kp2) * 64 + l) * 16);        \
        DST[2 * kp2] = u.x; DST[2 * kp2 + 1] = u.y;                              \
    }                                                                            \
} while (0)
#define BODY(CUR, NXT, c) do {                                                   \
    if ((c) + 1 < 16) LDA(NXT, (c) + 1);                                         \
    f32x4 a0 = {0.f,0.f,0.f,0.f}, a1 = {0.f,0.f,0.f,0.f};                        \
    _Pragma("unroll") for (int ks = 0; ks < 8; ++ks) {                           \
        a0 = __builtin_amdgcn_mfma_f32_16x16x32_fp8_fp8(CUR[ks], zf[0][ks], a0, 0, 0, 0); \
        a1 = __builtin_amdgcn_mfma_f32_16x16x32_fp8_fp8(CUR[ks], zf[1][ks], a1, 0, 0, 0); \
    }                                                                            \
    {                                                                            \
        const f32x4 cn = *(const f32x4*)(cn_lds + (c) * 16 + gc4);               \
        _Pragma("unroll") for (int r = 0; r < 4; ++r) {                          \
            const unsigned code0 = (unsigned)(q * 256 + (c) * 16 + gc4 + r);     \
            float s; unsigned e;                                                 \
            s = a0[r] + cn[r];                                                   \
            e = (__builtin_bit_cast(unsigned, s) & 0xFFFFFC00u) | code0;         \
            menc0 = fminf(menc0, __builtin_bit_cast(float, e));                  \
            s = a1[r] + cn[r];                                                   \
            e = (__builtin_bit_cast(unsigned, s) & 0xFFFFFC00u) | code0;         \
            menc1 = fminf(menc1, __builtin_bit_cast(float, e));                  \
        }                                                                        \
    }                                                                            \
} while (0)

    LDA(A0, 0);
    #pragma unroll 1
    for (int c2 = 0; c2 < 16; c2 += 2) {
        BODY(A0, A1, c2);
        BODY(A1, A0, c2 + 1);
    }
#undef BODY
#undef LDA

    // merge across the 4 g-groups sharing each pos column
    menc0 = fminf(menc0, __shfl_xor(menc0, 16));
    menc0 = fminf(menc0, __shfl_xor(menc0, 32));
    menc1 = fminf(menc1, __shfl_xor(menc1, 16));
    menc1 = fminf(menc1, __shfl_xor(menc1, 32));
    const int posbase = img * 1024 + hw0 + w * 32;
    if (l < 16) {
        penc[q * 32768 + posbase + l]      = menc0;
        penc[q * 32768 + posbase + 16 + l] = menc1;
    }

    // z^2 partial (identical across quarters -> only q==0 contributes)
    #pragma unroll
    for (int off = 1; off < 64; off <<= 1) z2 += __shfl_xor(z2, off);
    if (l == 0) redz[w] = z2;
    __syncthreads();
    if (t == 0 && q == 0) {
        float s = 0.f;
        #pragma unroll
        for (int i = 0; i < 8; ++i) s += redz[i];
        part2[grp] = s;
    }
}

// ---------------- K2: merge + z_q write + loss partial + last-block loss reduce ----------------
__global__ __launch_bounds__(256) void k2_out(const float* __restrict__ cbf,
                                              const float* __restrict__ penc,
                                              float* __restrict__ out,
                                              float* __restrict__ part,
                                              const float* __restrict__ part2,
                                              unsigned* __restrict__ ctr) {
    __shared__ __align__(16) float zqbuf[32 * 260];
    __shared__ unsigned idxl[64];
    __shared__ float red2[256];
    __shared__ unsigned lastflag;
    const int t = threadIdx.x, b = blockIdx.x;
    const int pos0 = b * 64, img = pos0 >> 10, hw0 = pos0 & 1023;

    if (t < 64) {
        const int pos = pos0 + t;
        const float e = fminf(fminf(penc[pos], penc[32768 + pos]),
                              fminf(penc[65536 + pos], penc[98304 + pos]));
        const unsigned eu = __builtin_bit_cast(unsigned, e);
        idxl[t] = eu & 0x3FFu;
        float myS = __builtin_bit_cast(float, eu & 0xFFFFFC00u);
        #pragma unroll
        for (int off = 1; off < 64; off <<= 1) myS += __shfl_xor(myS, off);
        if (t == 0) part[b] = myS * (1.f / 256.f);
    }

    const float4* cb4 = (const float4*)cbf;
    for (int h = 0; h < 2; ++h) {
        __syncthreads();
        #pragma unroll
        for (int i = 0; i < 8; ++i) {
            const int flat = i * 256 + t;        // [0,2048)
            const int p = flat >> 6;             // row 0..31
            const int qq = flat & 63;            // float4 index
            const unsigned code = idxl[h * 32 + p];
            *(float4*)&zqbuf[p * 260 + qq * 4] = cb4[code * 64 + qq];
        }
        __syncthreads();
        const int p = t & 31, c0 = t >> 5;       // c0 0..7
        float* ob = out + img * 262144 + hw0 + h * 32 + p;
        #pragma unroll
        for (int cc = 0; cc < 32; ++cc) {
            const int ch = c0 + cc * 8;
            ob[ch * 1024] = zqbuf[p * 260 + ch];
        }
    }

    // ---- last-block loss finisher (deterministic fixed-order tree) ----
    if (t == 0) {
        __threadfence();
        lastflag = (atomicAdd(ctr, 1u) == 511u) ? 1u : 0u;
    }
    __syncthreads();
    if (lastflag) {
        __threadfence();
        float v = part[t] + part[t + 256];
        if (t < 128) v += part2[t];
        red2[t] = v;
        __syncthreads();
        #pragma unroll
        for (int off = 128; off > 0; off >>= 1) {
            if (t < off) red2[t] += red2[t + off];
            __syncthreads();
        }
        if (t == 0) out[8388608] = 1.25f * red2[0] / 8388608.f;
    }
}

extern "C" void kernel_launch(void* const* d_in, const int* in_sizes, int n_in,
                              void* d_out, int out_size, void* d_ws, size_t ws_size,
                              hipStream_t stream) {
    const float* z  = (const float*)d_in[0];
    const float* cb = (const float*)d_in[1];
    float* out = (float*)d_out;
    unsigned char* ws = (unsigned char*)d_ws;
    float* penc  = (float*)(ws + WS_PENC);
    float* part2 = (float*)(ws + WS_PART2);
    float* part  = (float*)(ws + WS_PART);
    unsigned* ctr = (unsigned*)(ws + WS_CTR);

    hipLaunchKernelGGL(k1_main, dim3(512), dim3(512), 0, stream, z, cb, penc, part2, ctr);
    hipLaunchKernelGGL(k2_out,  dim3(512), dim3(256), 0, stream, cb, penc, out, part, part2, ctr);
}

// Round 12
// 56.192 us; speedup vs baseline: 1.4649x; 1.4649x over previous
//
#include <hip/hip_runtime.h>
#include <hip/hip_bf16.h>
#include <hip/hip_fp8.h>
#include <stdint.h>

// VQ: z (32,256,32,32) f32 NCHW, codebook (1024,256) f32
// out: z_q (8388608 f32 NCHW) + commit_loss (1 f32 at out[8388608])
//
// R12: two kernels total.
// k0 (R10's verified prep, quarters removed): cn256 + fp8(-512x) fragment-
// ordered codebook in ws; also resets the finisher counter.
// k1: 512 blocks x 256 thr (2 blocks/CU). Each block: 64 positions; z read
// ONCE -> fp8 B-frags in regs; whole codebook streamed through a 2x16KB LDS
// double-buffer (16 chunks x 64 codes, global_load_lds x16B). Every wave
// sees all codes -> argmin completes in-wave (g4 shfl merge), so the z_q
// gather/transpose/NCHW-write epilogue and the loss partial fuse in.
// Last block (threadfence+atomicAdd==511) runs the deterministic loss tree.
// Numerics identical to passing R9/R10 (encoded argmin (S&~0x3FF)|code,
// S = 256*(|c|^2 - 2 c.z) via fp8 MFMA; absmax 1.95e-3).

#define WS_CN    0                 // 1024 f32 (4KB)
#define WS_CB    4096              // 256 KB fp8 frags
#define WS_PART  266240            // 512 f32
#define WS_CTR   268288            // 1 u32

typedef float f32x4 __attribute__((ext_vector_type(4)));
typedef long  i64;
typedef long  l64x2 __attribute__((ext_vector_type(2)));

template <bool HI>
static __device__ __forceinline__ unsigned pk2(float a, float b, unsigned old) {
#if __has_builtin(__builtin_amdgcn_cvt_pk_fp8_f32)
    return (unsigned)__builtin_amdgcn_cvt_pk_fp8_f32(a, b, (int)old, HI);
#else
    __hip_fp8_e4m3 qa(a), qb(b);
    unsigned w = (unsigned)qa.__x | ((unsigned)qb.__x << 8);
    return HI ? ((old & 0x0000FFFFu) | (w << 16)) : ((old & 0xFFFF0000u) | w);
#endif
}

// ---------------- K0: cnorm*256 + (-512*codebook) fp8 fragment-ordered ----------------
// frag unit (16B) = [chunk64][kp4][lane64]; producer lane l (k=4l..4l+3):
// byteoff = ((chunk*4 + kp)*64 + g4*16 + r16)*16 + ksb*8 + lb*4.
__global__ __launch_bounds__(64) void k0_prep(const float* __restrict__ cb,
                                              float* __restrict__ cn256,
                                              unsigned char* __restrict__ cbf8,
                                              unsigned* __restrict__ ctr) {
    const int code = blockIdx.x;
    const int l = threadIdx.x;
    if (code == 0 && l == 0) *ctr = 0u;
    const float4 v = ((const float4*)cb)[code * 64 + l];   // k = 4l..4l+3
    float nrm = v.x * v.x + v.y * v.y + v.z * v.z + v.w * v.w;
    #pragma unroll
    for (int off = 1; off < 64; off <<= 1) nrm += __shfl_xor(nrm, off);
    if (l == 0) cn256[code] = 256.f * nrm;
    unsigned u = pk2<false>(-512.f * v.x, -512.f * v.y, 0u);
    u = pk2<true>(-512.f * v.z, -512.f * v.w, u);
    const int chunk = code >> 4, r16 = code & 15;
    const int kp = l >> 4, ksb = (l >> 3) & 1, g4 = (l >> 1) & 3, lb = l & 1;
    const int byteoff = ((chunk * 4 + kp) * 64 + g4 * 16 + r16) * 16
                      + ksb * 8 + lb * 4;
    *(unsigned*)(cbf8 + byteoff) = u;
}

// ---------------- K1: fused distances + argmin + z_q + loss ----------------
__global__ __launch_bounds__(256) void k1_main(const float* __restrict__ z,
                                               const float* __restrict__ cb,
                                               const unsigned char* __restrict__ cbf8,
                                               const float* __restrict__ cn256,
                                               float* __restrict__ out,
                                               float* __restrict__ part,
                                               unsigned* __restrict__ ctr) {
    __shared__ __align__(16) unsigned char cbbuf[32768];   // 2 x 16KB chunks
    __shared__ __align__(16) float cnl[1024];
    __shared__ __align__(16) float zqbuf[32 * 260];
    __shared__ unsigned idxl[64];
    __shared__ float redz[4];
    __shared__ unsigned lastflag;

    const int t = threadIdx.x, w = t >> 6, l = t & 63;
    const int col = l & 15, g4 = l >> 4, gc4 = g4 * 4;
    const int b = blockIdx.x;
    const int pos0 = b * 64, img = pos0 >> 10, hw0 = pos0 & 1023;

    // stage cn256 (4KB) and chunk 0 (16KB) -> LDS
    {
        const unsigned char* csrc = (const unsigned char*)cn256;
        unsigned char* cdst = (unsigned char*)cnl;
        const int off = w * 1024;
        __builtin_amdgcn_global_load_lds(
            (const __attribute__((address_space(1))) unsigned*)(csrc + off + l * 16),
            (__attribute__((address_space(3))) unsigned*)(cdst + off), 16, 0, 0);
        #pragma unroll
        for (int i = 0; i < 4; ++i) {
            const int o2 = i * 4096 + w * 1024;
            __builtin_amdgcn_global_load_lds(
                (const __attribute__((address_space(1))) unsigned*)(cbf8 + o2 + l * 16),
                (__attribute__((address_space(3))) unsigned*)(cbbuf + o2), 16, 0, 0);
        }
    }

    // ---- z -> fp8 B-frags (16 pos per wave) + z^2, overlapped with staging ----
    const float* zp = z + img * 262144 + hw0;
    const int p = w * 16 + col;
    float z2 = 0.f;
    i64 zf[8];
    #pragma unroll
    for (int ks = 0; ks < 8; ++ks) {
        const float* s0 = zp + (ks * 32 + g4 * 8) * 1024 + p;
        float v0 = s0[0], v1 = s0[1024], v2 = s0[2048], v3 = s0[3072];
        float v4 = s0[4096], v5 = s0[5120], v6 = s0[6144], v7 = s0[7168];
        z2 += v0*v0 + v1*v1 + v2*v2 + v3*v3 + v4*v4 + v5*v5 + v6*v6 + v7*v7;
        unsigned lo = pk2<false>(v0, v1, 0u); lo = pk2<true>(v2, v3, lo);
        unsigned hi = pk2<false>(v4, v5, 0u); hi = pk2<true>(v6, v7, hi);
        zf[ks] = (i64)(((unsigned long)hi << 32) | (unsigned long)lo);
    }
    __syncthreads();   // cn + chunk 0 resident

    float menc = __builtin_bit_cast(float, 0x7F7FFC00u);

    #pragma unroll 1
    for (int s = 0; s < 16; ++s) {
        if (s) __syncthreads();               // chunk s resident; prev buf reads done
        if (s + 1 < 16) {                     // prefetch chunk s+1 into other buf
            const unsigned char* src = cbf8 + (s + 1) * 16384;
            unsigned char* dst = cbbuf + ((s + 1) & 1) * 16384;
            #pragma unroll
            for (int i = 0; i < 4; ++i) {
                const int o2 = i * 4096 + w * 1024;
                __builtin_amdgcn_global_load_lds(
                    (const __attribute__((address_space(1))) unsigned*)(src + o2 + l * 16),
                    (__attribute__((address_space(3))) unsigned*)(dst + o2), 16, 0, 0);
            }
        }
        const unsigned char* buf = cbbuf + (s & 1) * 16384;
        #pragma unroll
        for (int cl = 0; cl < 4; ++cl) {      // 4 independent acc chains
            i64 A[8];
            #pragma unroll
            for (int kp = 0; kp < 4; ++kp) {
                l64x2 u = *(const l64x2*)(buf + ((cl * 4 + kp) * 64 + l) * 16);
                A[2 * kp] = u.x; A[2 * kp + 1] = u.y;
            }
            f32x4 a0 = {0.f, 0.f, 0.f, 0.f};
            #pragma unroll
            for (int ks = 0; ks < 8; ++ks)
                a0 = __builtin_amdgcn_mfma_f32_16x16x32_fp8_fp8(A[ks], zf[ks], a0, 0, 0, 0);
            const int cbase = (s * 4 + cl) * 16;
            const f32x4 cn = *(const f32x4*)(cnl + cbase + gc4);
            #pragma unroll
            for (int r = 0; r < 4; ++r) {
                const float sc = a0[r] + cn[r];
                const unsigned e = (__builtin_bit_cast(unsigned, sc) & 0xFFFFFC00u)
                                 | (unsigned)(cbase + gc4 + r);
                menc = fminf(menc, __builtin_bit_cast(float, e));
            }
        }
    }

    // merge across the 4 g-groups (lanes l, l+16, l+32, l+48 share a position)
    menc = fminf(menc, __shfl_xor(menc, 16));
    menc = fminf(menc, __shfl_xor(menc, 32));
    const unsigned eu = __builtin_bit_cast(unsigned, menc);
    if (l < 16) idxl[w * 16 + l] = eu & 0x3FFu;

    // loss partial: z2 (all lanes) + minS/256 (lanes 0..15 hold distinct positions)
    float v = z2 + ((l < 16)
        ? __builtin_bit_cast(float, eu & 0xFFFFFC00u) * (1.f / 256.f) : 0.f);
    #pragma unroll
    for (int off = 1; off < 64; off <<= 1) v += __shfl_xor(v, off);
    if (l == 0) redz[w] = v;

    // ---- z_q epilogue: gather codebook rows -> LDS transpose -> NCHW ----
    const float4* cb4 = (const float4*)cb;
    for (int h = 0; h < 2; ++h) {
        __syncthreads();                       // idxl/redz visible; zqbuf free
        if (h == 0 && t == 0) part[b] = redz[0] + redz[1] + redz[2] + redz[3];
        #pragma unroll
        for (int i = 0; i < 8; ++i) {
            const int flat = i * 256 + t;      // [0,2048)
            const int pp = flat >> 6;          // row 0..31
            const int qq = flat & 63;          // float4 index
            const unsigned code = idxl[h * 32 + pp];
            *(float4*)&zqbuf[pp * 260 + qq * 4] = cb4[code * 64 + qq];
        }
        __syncthreads();
        const int pp = t & 31, c0 = t >> 5;    // c0 0..7
        float* ob = out + img * 262144 + hw0 + h * 32 + pp;
        #pragma unroll
        for (int cc = 0; cc < 32; ++cc) {
            const int ch = c0 + cc * 8;
            ob[ch * 1024] = zqbuf[pp * 260 + ch];
        }
    }

    // ---- last-block deterministic loss finisher ----
    if (t == 0) {
        __threadfence();
        lastflag = (atomicAdd(ctr, 1u) == 511u) ? 1u : 0u;
    }
    __syncthreads();
    if (lastflag) {
        __threadfence();
        float* red2 = zqbuf;                   // reuse LDS
        red2[t] = part[t] + part[t + 256];
        __syncthreads();
        #pragma unroll
        for (int off = 128; off > 0; off >>= 1) {
            if (t < off) red2[t] += red2[t + off];
            __syncthreads();
        }
        if (t == 0) out[8388608] = 1.25f * red2[0] / 8388608.f;
    }
}

extern "C" void kernel_launch(void* const* d_in, const int* in_sizes, int n_in,
                              void* d_out, int out_size, void* d_ws, size_t ws_size,
                              hipStream_t stream) {
    const float* z  = (const float*)d_in[0];
    const float* cb = (const float*)d_in[1];
    float* out = (float*)d_out;
    unsigned char* ws = (unsigned char*)d_ws;
    float* cn256 = (float*)(ws + WS_CN);
    unsigned char* cbf8 = ws + WS_CB;
    float* part  = (float*)(ws + WS_PART);
    unsigned* ctr = (unsigned*)(ws + WS_CTR);

    hipLaunchKernelGGL(k0_prep, dim3(1024), dim3(64), 0, stream, cb, cn256, cbf8, ctr);
    hipLaunchKernelGGL(k1_main, dim3(512), dim3(256), 0, stream,
                       z, cb, cbf8, cn256, out, part, ctr);
}

// Round 13
// 49.647 us; speedup vs baseline: 1.6580x; 1.1318x over previous
//
#include <hip/hip_runtime.h>
#include <hip/hip_bf16.h>
#include <hip/hip_fp8.h>
#include <stdint.h>

// VQ: z (32,256,32,32) f32 NCHW, codebook (1024,256) f32
// out: z_q (8388608 f32 NCHW) + commit_loss (1 f32 at out[8388608])
//
// R13: barrier-FEW full-codebook blocks.
// Evidence (R10 vs R12 A/B): main-loop barrier+vmcnt-drain per chunk is the
// ~60us poison (R12: 16 barriers -> 52us k1); stage-once was fast (R10).
// Here: 256 blocks x 512 thr; each block = 128 positions x ALL 1024 codes.
// z read ONCE. Codebook = 8 chunks x 32KB, LDS double-buffered => only 8
// main-loop barriers, each amortized over 128 MFMA/wave. In-wave argmin
// completes (all codes seen) => no penc/k2: fused z_q epilogue + loss +
// last-block finisher (proven R11/R12). k0 = R12's verified prep.
// Numerics unchanged (fp8 e4m3 x-512, encoded argmin, absmax 1.95e-3).

#define WS_CN    0                 // 1024 f32 (4KB)
#define WS_CB    4096              // 256 KB fp8 frags
#define WS_PART  266240            // 256 f32
#define WS_CTR   267264            // 1 u32

typedef float f32x4 __attribute__((ext_vector_type(4)));
typedef long  i64;
typedef long  l64x2 __attribute__((ext_vector_type(2)));

template <bool HI>
static __device__ __forceinline__ unsigned pk2(float a, float b, unsigned old) {
#if __has_builtin(__builtin_amdgcn_cvt_pk_fp8_f32)
    return (unsigned)__builtin_amdgcn_cvt_pk_fp8_f32(a, b, (int)old, HI);
#else
    __hip_fp8_e4m3 qa(a), qb(b);
    unsigned w = (unsigned)qa.__x | ((unsigned)qb.__x << 8);
    return HI ? ((old & 0x0000FFFFu) | (w << 16)) : ((old & 0xFFFF0000u) | w);
#endif
}

// ---------------- K0: cnorm*256 + (-512*codebook) fp8 fragment-ordered ----------------
// 16-code group g: bytes [g*4096 + ((kp)*64 + g4*16 + r16)*16 + ksb*8 + lb*4]
__global__ __launch_bounds__(64) void k0_prep(const float* __restrict__ cb,
                                              float* __restrict__ cn256,
                                              unsigned char* __restrict__ cbf8,
                                              unsigned* __restrict__ ctr) {
    const int code = blockIdx.x;
    const int l = threadIdx.x;
    if (code == 0 && l == 0) *ctr = 0u;
    const float4 v = ((const float4*)cb)[code * 64 + l];   // k = 4l..4l+3
    float nrm = v.x * v.x + v.y * v.y + v.z * v.z + v.w * v.w;
    #pragma unroll
    for (int off = 1; off < 64; off <<= 1) nrm += __shfl_xor(nrm, off);
    if (l == 0) cn256[code] = 256.f * nrm;
    unsigned u = pk2<false>(-512.f * v.x, -512.f * v.y, 0u);
    u = pk2<true>(-512.f * v.z, -512.f * v.w, u);
    const int grp16 = code >> 4, r16 = code & 15;
    const int kp = l >> 4, ksb = (l >> 3) & 1, g4 = (l >> 1) & 3, lb = l & 1;
    const int byteoff = grp16 * 4096 + (kp * 64 + g4 * 16 + r16) * 16
                      + ksb * 8 + lb * 4;
    *(unsigned*)(cbf8 + byteoff) = u;
}

// ---------------- K1: fused distances + argmin + z_q + loss ----------------
__global__ __launch_bounds__(512) void k1_main(const float* __restrict__ z,
                                               const float* __restrict__ cb,
                                               const unsigned char* __restrict__ cbf8,
                                               const float* __restrict__ cn256,
                                               float* __restrict__ out,
                                               float* __restrict__ part,
                                               unsigned* __restrict__ ctr) {
    __shared__ __align__(16) unsigned char cbbuf[65536];   // 2 x 32KB chunks
    __shared__ __align__(16) float cnl[1024];
    __shared__ __align__(16) float zqbuf[32 * 260];
    __shared__ unsigned idxl[128];
    __shared__ float redz[8];
    __shared__ unsigned lastflag;

    const int t = threadIdx.x, w = t >> 6, l = t & 63;
    const int col = l & 15, g4 = l >> 4, gc4 = g4 * 4;
    const int b = blockIdx.x;
    const int pos0 = b * 128, img = pos0 >> 10, hw0 = pos0 & 1023;

    // stage cn256 (4KB, waves 0-3) and chunk 0 (32KB) -> LDS
    {
        if (w < 4) {
            const unsigned char* csrc = (const unsigned char*)cn256;
            const int off = w * 1024;
            __builtin_amdgcn_global_load_lds(
                (const __attribute__((address_space(1))) unsigned*)(csrc + off + l * 16),
                (__attribute__((address_space(3))) unsigned*)((unsigned char*)cnl + off),
                16, 0, 0);
        }
        #pragma unroll
        for (int i = 0; i < 4; ++i) {
            const int o2 = i * 8192 + w * 1024;
            __builtin_amdgcn_global_load_lds(
                (const __attribute__((address_space(1))) unsigned*)(cbf8 + o2 + l * 16),
                (__attribute__((address_space(3))) unsigned*)(cbbuf + o2), 16, 0, 0);
        }
    }

    // ---- z -> fp8 B-frags (16 pos per wave) + z^2, overlapped with staging ----
    const float* zp = z + img * 262144 + hw0;
    const int p = w * 16 + col;
    float z2 = 0.f;
    i64 zf[8];
    #pragma unroll
    for (int ks = 0; ks < 8; ++ks) {
        const float* s0 = zp + (ks * 32 + g4 * 8) * 1024 + p;
        float v0 = s0[0], v1 = s0[1024], v2 = s0[2048], v3 = s0[3072];
        float v4 = s0[4096], v5 = s0[5120], v6 = s0[6144], v7 = s0[7168];
        z2 += v0*v0 + v1*v1 + v2*v2 + v3*v3 + v4*v4 + v5*v5 + v6*v6 + v7*v7;
        unsigned lo = pk2<false>(v0, v1, 0u); lo = pk2<true>(v2, v3, lo);
        unsigned hi = pk2<false>(v4, v5, 0u); hi = pk2<true>(v6, v7, hi);
        zf[ks] = (i64)(((unsigned long)hi << 32) | (unsigned long)lo);
    }
    __syncthreads();   // cn + chunk 0 resident

    float menc = __builtin_bit_cast(float, 0x7F7FFC00u);

    #pragma unroll 1
    for (int s = 0; s < 8; ++s) {
        if (s) __syncthreads();               // chunk s resident; prev buf reads done
        if (s + 1 < 8) {                      // prefetch chunk s+1 into other buf
            const unsigned char* src = cbf8 + (s + 1) * 32768;
            unsigned char* dst = cbbuf + ((s + 1) & 1) * 32768;
            #pragma unroll
            for (int i = 0; i < 4; ++i) {
                const int o2 = i * 8192 + w * 1024;
                __builtin_amdgcn_global_load_lds(
                    (const __attribute__((address_space(1))) unsigned*)(src + o2 + l * 16),
                    (__attribute__((address_space(3))) unsigned*)(dst + o2), 16, 0, 0);
            }
        }
        const unsigned char* buf = cbbuf + (s & 1) * 32768;
        #pragma unroll
        for (int cl2 = 0; cl2 < 4; ++cl2) {   // 2 paired 16-code chains for ILP
            i64 A0[8], A1[8];
            #pragma unroll
            for (int kp = 0; kp < 4; ++kp) {
                l64x2 u0 = *(const l64x2*)(buf + (((cl2 * 2) * 4 + kp) * 64 + l) * 16);
                A0[2 * kp] = u0.x; A0[2 * kp + 1] = u0.y;
                l64x2 u1 = *(const l64x2*)(buf + (((cl2 * 2 + 1) * 4 + kp) * 64 + l) * 16);
                A1[2 * kp] = u1.x; A1[2 * kp + 1] = u1.y;
            }
            f32x4 a0 = {0.f, 0.f, 0.f, 0.f};
            f32x4 a1 = {0.f, 0.f, 0.f, 0.f};
            #pragma unroll
            for (int ks = 0; ks < 8; ++ks) {
                a0 = __builtin_amdgcn_mfma_f32_16x16x32_fp8_fp8(A0[ks], zf[ks], a0, 0, 0, 0);
                a1 = __builtin_amdgcn_mfma_f32_16x16x32_fp8_fp8(A1[ks], zf[ks], a1, 0, 0, 0);
            }
            const int cb0 = (s * 8 + cl2 * 2) * 16;
            const f32x4 cn0 = *(const f32x4*)(cnl + cb0 + gc4);
            const f32x4 cn1 = *(const f32x4*)(cnl + cb0 + 16 + gc4);
            #pragma unroll
            for (int r = 0; r < 4; ++r) {
                float sc = a0[r] + cn0[r];
                unsigned e = (__builtin_bit_cast(unsigned, sc) & 0xFFFFFC00u)
                           | (unsigned)(cb0 + gc4 + r);
                menc = fminf(menc, __builtin_bit_cast(float, e));
                sc = a1[r] + cn1[r];
                e = (__builtin_bit_cast(unsigned, sc) & 0xFFFFFC00u)
                  | (unsigned)(cb0 + 16 + gc4 + r);
                menc = fminf(menc, __builtin_bit_cast(float, e));
            }
        }
    }

    // merge across the 4 g-groups (lanes l, l+16, l+32, l+48 share a position)
    menc = fminf(menc, __shfl_xor(menc, 16));
    menc = fminf(menc, __shfl_xor(menc, 32));
    const unsigned eu = __builtin_bit_cast(unsigned, menc);
    if (l < 16) idxl[w * 16 + l] = eu & 0x3FFu;

    // loss partial: z2 (all lanes) + minS/256 (lanes 0..15 hold distinct positions)
    float v = z2 + ((l < 16)
        ? __builtin_bit_cast(float, eu & 0xFFFFFC00u) * (1.f / 256.f) : 0.f);
    #pragma unroll
    for (int off = 1; off < 64; off <<= 1) v += __shfl_xor(v, off);
    if (l == 0) redz[w] = v;

    // ---- z_q epilogue: gather codebook rows -> LDS transpose -> NCHW ----
    const float4* cb4 = (const float4*)cb;
    for (int h = 0; h < 4; ++h) {
        __syncthreads();                       // idxl/redz visible; zqbuf free
        if (h == 0 && t == 0)
            part[b] = redz[0] + redz[1] + redz[2] + redz[3]
                    + redz[4] + redz[5] + redz[6] + redz[7];
        #pragma unroll
        for (int i = 0; i < 4; ++i) {
            const int flat = i * 512 + t;      // [0,2048)
            const int pp = flat >> 6;          // row 0..31
            const int qq = flat & 63;          // float4 index
            const unsigned code = idxl[h * 32 + pp];
            *(float4*)&zqbuf[pp * 260 + qq * 4] = cb4[code * 64 + qq];
        }
        __syncthreads();
        const int pp = t & 31, c0 = t >> 5;    // c0 0..15
        float* ob = out + img * 262144 + hw0 + h * 32 + pp;
        #pragma unroll
        for (int cc = 0; cc < 16; ++cc) {
            const int ch = c0 + cc * 16;
            ob[ch * 1024] = zqbuf[pp * 260 + ch];
        }
    }

    // ---- last-block deterministic loss finisher ----
    if (t == 0) {
        __threadfence();
        lastflag = (atomicAdd(ctr, 1u) == 255u) ? 1u : 0u;
    }
    __syncthreads();
    if (lastflag) {
        __threadfence();
        float* red2 = zqbuf;                   // reuse LDS
        if (t < 256) red2[t] = part[t];
        __syncthreads();
        #pragma unroll
        for (int off = 128; off > 0; off >>= 1) {
            if (t < off) red2[t] += red2[t + off];
            __syncthreads();
        }
        if (t == 0) out[8388608] = 1.25f * red2[0] / 8388608.f;
    }
}

extern "C" void kernel_launch(void* const* d_in, const int* in_sizes, int n_in,
                              void* d_out, int out_size, void* d_ws, size_t ws_size,
                              hipStream_t stream) {
    const float* z  = (const float*)d_in[0];
    const float* cb = (const float*)d_in[1];
    float* out = (float*)d_out;
    unsigned char* ws = (unsigned char*)d_ws;
    float* cn256 = (float*)(ws + WS_CN);
    unsigned char* cbf8 = ws + WS_CB;
    float* part  = (float*)(ws + WS_PART);
    unsigned* ctr = (unsigned*)(ws + WS_CTR);

    hipLaunchKernelGGL(k0_prep, dim3(1024), dim3(64), 0, stream, cb, cn256, cbf8, ctr);
    hipLaunchKernelGGL(k1_main, dim3(256), dim3(512), 0, stream,
                       z, cb, cbf8, cn256, out, part, ctr);
}